// Round 1
// baseline (12997.688 us; speedup 1.0000x reference)
//
#include <hip/hip_runtime.h>
#include <math.h>

#define B_ 2
#define S_ 2048
#define D_ 2048
#define H_ 16
#define DH_ 128
#define QP_ 1024
#define KVP_ 1365
#define RD_ 64
#define ND_ 64
#define FF_ 8192
#define T_ (B_*S_)          // 4096 tokens
#define CKW_ (KVP_+RD_)     // 1429
#define KVW_ 3072           // D + H*ND

// ---------------- LayerNorm (one block per row) ----------------
__global__ __launch_bounds__(256) void ln_kernel(const float* __restrict__ in, int in_stride,
                                                 const float* __restrict__ w, const float* __restrict__ bb,
                                                 float* __restrict__ out, int out_stride, int N)
{
    int row = blockIdx.x;
    const float* ip = in + (size_t)row * in_stride;
    float* op = out + (size_t)row * out_stride;
    int tid = threadIdx.x;
    float sum = 0.f, sq = 0.f;
    for (int i = tid; i < N; i += 256) { float v = ip[i]; sum += v; sq += v * v; }
    __shared__ float s1[256], s2[256];
    s1[tid] = sum; s2[tid] = sq; __syncthreads();
    for (int s = 128; s > 0; s >>= 1) {
        if (tid < s) { s1[tid] += s1[tid + s]; s2[tid] += s2[tid + s]; }
        __syncthreads();
    }
    float mean = s1[0] / N;
    float var  = s2[0] / N - mean * mean;
    float rstd = rsqrtf(var + 1e-5f);
    for (int i = tid; i < N; i += 256) {
        float v = ip[i];
        op[i] = (v - mean) * rstd * w[i] + bb[i];
    }
}

// ---------------- Generic tiled f32 GEMM ----------------
// C[M,N] = A[M,K] @ (TRANSB ? B^T : B)   (B is [N,K] when TRANSB)
// EPI: 0 = plain store, 1 = + resid[r,c], 2 = gelu(acc+bias[c]), 3 = C += acc + bias[c]
template<bool TRANSB, int EPI>
__global__ __launch_bounds__(256) void gemm_f32(const float* __restrict__ A, const float* __restrict__ B,
                                                float* __restrict__ C, int M, int N, int K,
                                                int lda, int ldb, int ldc,
                                                const float* __restrict__ bias,
                                                const float* __restrict__ resid, int ldr)
{
    const int BM = 64, BN = 64, BK = 16;
    __shared__ float As[BK][BM + 4];
    __shared__ float Bs[BK][BN + 4];
    int tid = threadIdx.x;
    int bm = blockIdx.y * BM;
    int bn = blockIdx.x * BN;
    int tx = tid & 15, ty = tid >> 4;
    float acc[4][4] = {};
    for (int k0 = 0; k0 < K; k0 += BK) {
        // A tile: 64 x 16
        for (int i = tid; i < BM * BK; i += 256) {
            int m = i >> 4, kk = i & 15;
            int kg = k0 + kk;
            float v = 0.f;
            if (kg < K) v = A[(size_t)(bm + m) * lda + kg];
            As[kk][m] = v;
        }
        // B tile: 16 x 64
        if (!TRANSB) {
            for (int i = tid; i < BK * BN; i += 256) {
                int kk = i >> 6, n = i & 63;
                int kg = k0 + kk, ng = bn + n;
                float v = 0.f;
                if (kg < K && ng < N) v = B[(size_t)kg * ldb + ng];
                Bs[kk][n] = v;
            }
        } else {
            for (int i = tid; i < BK * BN; i += 256) {
                int n = i >> 4, kk = i & 15;
                int kg = k0 + kk, ng = bn + n;
                float v = 0.f;
                if (kg < K && ng < N) v = B[(size_t)ng * ldb + kg];
                Bs[kk][n] = v;
            }
        }
        __syncthreads();
        #pragma unroll
        for (int kk = 0; kk < BK; ++kk) {
            float4 av = *(const float4*)&As[kk][ty * 4];
            float4 bv = *(const float4*)&Bs[kk][tx * 4];
            float a[4] = {av.x, av.y, av.z, av.w};
            float b[4] = {bv.x, bv.y, bv.z, bv.w};
            #pragma unroll
            for (int i = 0; i < 4; ++i)
                #pragma unroll
                for (int j = 0; j < 4; ++j)
                    acc[i][j] += a[i] * b[j];
        }
        __syncthreads();
    }
    for (int i = 0; i < 4; ++i) {
        int r = bm + ty * 4 + i;
        if (r >= M) continue;
        for (int j = 0; j < 4; ++j) {
            int c = bn + tx * 4 + j;
            if (c >= N) continue;
            float v = acc[i][j];
            if (EPI == 1) v += resid[(size_t)r * ldr + c];
            if (EPI == 2) { v += bias[c]; v = 0.5f * v * (1.f + erff(v * 0.70710678118654752f)); }
            if (EPI == 3) { v += bias[c]; v += C[(size_t)r * ldc + c]; }
            C[(size_t)r * ldc + c] = v;
        }
    }
}

// ---------------- RoPE ----------------
// pair (i, i+32) of the 64-dim rotary slice: out_i = u*c - v*s ; out_{i+32} = v*c + u*s
__global__ __launch_bounds__(256) void rope_q_kernel(float* __restrict__ Q)
{
    int idx = blockIdx.x * 256 + threadIdx.x;        // T*H*32
    int i = idx & 31;
    int h = (idx >> 5) & (H_ - 1);
    int t = idx >> 9;
    float f = expf(-(float)i * (9.210340371976184f / 64.0f)); // 10000^(-i/64)
    float ang = (float)(t & (S_ - 1)) * f;
    float sv, cv; sincosf(ang, &sv, &cv);
    float* p = Q + (size_t)t * D_ + h * DH_ + ND_;
    float u = p[i], v = p[i + 32];
    p[i]      = u * cv - v * sv;
    p[i + 32] = v * cv + u * sv;
}

__global__ __launch_bounds__(256) void rope_kr_kernel(const float* __restrict__ ckv, float* __restrict__ kr)
{
    int idx = blockIdx.x * 256 + threadIdx.x;        // T*32
    int i = idx & 31;
    int t = idx >> 5;
    float f = expf(-(float)i * (9.210340371976184f / 64.0f));
    float ang = (float)(t & (S_ - 1)) * f;
    float sv, cv; sincosf(ang, &sv, &cv);
    const float* src = ckv + (size_t)t * CKW_ + KVP_;
    float u = src[i], v = src[i + 32];
    kr[(size_t)t * RD_ + i]      = u * cv - v * sv;
    kr[(size_t)t * RD_ + i + 32] = v * cv + u * sv;
}

// ---------------- Attention: one wave per (b,h,q) row, online softmax ----------------
// q = [Qn(64) | roped Qr(64)] from Q_flat; k = [K(64) from KV | roped Kr(64) shared];
// v = KV dims 64..191 (128). Lane l owns dims 2l,2l+1 of the 128-dim vectors.
__global__ __launch_bounds__(256) void attn_kernel(const float* __restrict__ Q,
                                                   const float* __restrict__ KV,
                                                   const float* __restrict__ KR,
                                                   float* __restrict__ O)
{
    int wid  = (blockIdx.x * 256 + threadIdx.x) >> 6;
    int lane = threadIdx.x & 63;
    int q = wid & (S_ - 1);
    int h = (wid >> 11) & (H_ - 1);
    int b = wid >> 15;

    const float* qrow = Q + (size_t)(b * S_ + q) * D_ + h * DH_;
    float2 qv = *(const float2*)(qrow + 2 * lane);
    const float scale = 0.08838834764831845f;   // 1/sqrt(128)
    qv.x *= scale; qv.y *= scale;

    const float* kvbase = KV + (size_t)b * S_ * KVW_ + h * 192;
    const float* krbase = KR + (size_t)b * S_ * RD_;

    float m = -INFINITY, l = 0.f, a0 = 0.f, a1 = 0.f;
    for (int k = 0; k <= q; ++k) {
        const float* kvrow = kvbase + (size_t)k * KVW_;
        float2 kv2;
        if (lane < 32) kv2 = *(const float2*)(kvrow + 2 * lane);
        else           kv2 = *(const float2*)(krbase + (size_t)k * RD_ + 2 * (lane - 32));
        float part = qv.x * kv2.x + qv.y * kv2.y;
        #pragma unroll
        for (int off = 32; off > 0; off >>= 1) part += __shfl_xor(part, off);
        float mnew = fmaxf(m, part);
        float corr = __expf(m - mnew);
        float p    = __expf(part - mnew);
        float2 vv = *(const float2*)(kvrow + ND_ + 2 * lane);
        l  = l  * corr + p;
        a0 = a0 * corr + p * vv.x;
        a1 = a1 * corr + p * vv.y;
        m = mnew;
    }
    float inv = 1.0f / l;
    float* orow = O + (size_t)(b * S_ + q) * D_ + h * DH_;
    orow[2 * lane]     = a0 * inv;
    orow[2 * lane + 1] = a1 * inv;
}

// ---------------- Launcher ----------------
extern "C" void kernel_launch(void* const* d_in, const int* in_sizes, int n_in,
                              void* d_out, int out_size, void* d_ws, size_t ws_size,
                              hipStream_t stream)
{
    const float* x     = (const float*)d_in[0];
    const float* anw   = (const float*)d_in[1];
    const float* anb   = (const float*)d_in[2];
    const float* W_dq  = (const float*)d_in[3];
    const float* qlw   = (const float*)d_in[4];
    const float* qlb   = (const float*)d_in[5];
    const float* W_uq  = (const float*)d_in[6];
    const float* W_dkv = (const float*)d_in[7];
    const float* kvlw  = (const float*)d_in[8];
    const float* kvlb  = (const float*)d_in[9];
    const float* W_ukv = (const float*)d_in[10];
    const float* W_o   = (const float*)d_in[11];
    const float* fnw   = (const float*)d_in[12];
    const float* fnb   = (const float*)d_in[13];
    const float* W1    = (const float*)d_in[14];
    const float* b1    = (const float*)d_in[15];
    const float* W2    = (const float*)d_in[16];
    const float* b2    = (const float*)d_in[17];

    float* out0 = (float*)d_out;                     // [T, D] = x2 then += ffn
    float* ckv  = out0 + (size_t)T_ * D_;            // [T, 1429] raw h@W_dkv (output 1)

    float* ws  = (float*)d_ws;
    float* h   = ws;                                 // [T, D]
    float* cq  = h   + (size_t)T_ * D_;              // [T, QP]
    float* Q   = cq  + (size_t)T_ * QP_;             // [T, D] (roped in place)
    float* kvl = Q   + (size_t)T_ * D_;              // [T, KVP]
    float* kvu = kvl + (size_t)T_ * KVP_;            // [T, 3072]
    float* kr  = kvu + (size_t)T_ * KVW_;            // [T, 64]
    float* o   = kr  + (size_t)T_ * RD_;             // [T, D]
    float* ff1 = cq;                                 // overlay: cq..o region (39.4M floats >= 33.6M)

    dim3 blk(256);

    // 1. h = LN(x)
    ln_kernel<<<T_, blk, 0, stream>>>(x, D_, anw, anb, h, D_, D_);
    // 2. cq = h @ W_dq ; LN in place
    {
        dim3 g((QP_ + 63) / 64, T_ / 64);
        gemm_f32<false, 0><<<g, blk, 0, stream>>>(h, W_dq, cq, T_, QP_, D_, D_, QP_, QP_, nullptr, nullptr, 0);
    }
    ln_kernel<<<T_, blk, 0, stream>>>(cq, QP_, qlw, qlb, cq, QP_, QP_);
    // 3. Q = cq @ W_uq ; rope in place
    {
        dim3 g((D_ + 63) / 64, T_ / 64);
        gemm_f32<false, 0><<<g, blk, 0, stream>>>(cq, W_uq, Q, T_, D_, QP_, QP_, D_, D_, nullptr, nullptr, 0);
    }
    rope_q_kernel<<<(T_ * H_ * 32) / 256, blk, 0, stream>>>(Q);
    // 4. ckv = h @ W_dkv (raw -> output 1)
    {
        dim3 g((CKW_ + 63) / 64, T_ / 64);
        gemm_f32<false, 0><<<g, blk, 0, stream>>>(h, W_dkv, ckv, T_, CKW_, D_, D_, CKW_, CKW_, nullptr, nullptr, 0);
    }
    // 5. kvl = LN(ckv[:, :KVP])
    ln_kernel<<<T_, blk, 0, stream>>>(ckv, CKW_, kvlw, kvlb, kvl, KVP_, KVP_);
    // 6. kvu = kvl @ W_ukv
    {
        dim3 g((KVW_ + 63) / 64, T_ / 64);
        gemm_f32<false, 0><<<g, blk, 0, stream>>>(kvl, W_ukv, kvu, T_, KVW_, KVP_, KVP_, KVW_, KVW_, nullptr, nullptr, 0);
    }
    // 7. roped shared k_rope
    rope_kr_kernel<<<(T_ * 32) / 256, blk, 0, stream>>>(ckv, kr);
    // 8. attention -> o  (one wave per (b,h,q))
    attn_kernel<<<(B_ * H_ * S_) / 4, blk, 0, stream>>>(Q, kvu, kr, o);
    // 9. x2 = o @ W_o^T + x   -> out0
    {
        dim3 g((D_ + 63) / 64, T_ / 64);
        gemm_f32<true, 1><<<g, blk, 0, stream>>>(o, W_o, out0, T_, D_, D_, D_, D_, D_, nullptr, x, D_);
    }
    // 10. h = LN(out0)
    ln_kernel<<<T_, blk, 0, stream>>>(out0, D_, fnw, fnb, h, D_, D_);
    // 11. ff1 = gelu(h @ W1 + b1)
    {
        dim3 g((FF_ + 63) / 64, T_ / 64);
        gemm_f32<false, 2><<<g, blk, 0, stream>>>(h, W1, ff1, T_, FF_, D_, D_, FF_, FF_, b1, nullptr, 0);
    }
    // 12. out0 += ff1 @ W2 + b2
    {
        dim3 g((D_ + 63) / 64, T_ / 64);
        gemm_f32<false, 3><<<g, blk, 0, stream>>>(ff1, W2, out0, T_, D_, FF_, FF_, D_, D_, b2, nullptr, 0);
    }
}

// Round 2
// 6046.338 us; speedup vs baseline: 2.1497x; 2.1497x over previous
//
#include <hip/hip_runtime.h>
#include <hip/hip_bf16.h>
#include <math.h>

#define B_ 2
#define S_ 2048
#define D_ 2048
#define H_ 16
#define DH_ 128
#define QP_ 1024
#define KVP_ 1365
#define RD_ 64
#define ND_ 64
#define FF_ 8192
#define T_ (B_*S_)          // 4096 tokens
#define CKW_ (KVP_+RD_)     // 1429
#define KVW_ 3072           // D + H*ND
#define KVP_PAD 1408        // 1365 -> mult of 64
#define CKW_PAD 1536        // 1429 -> mult of 128

typedef __attribute__((ext_vector_type(8))) short short8;
typedef __attribute__((ext_vector_type(4))) float floatx4;

__device__ __forceinline__ void gload_lds16(const __hip_bfloat16* g, __hip_bfloat16* l) {
    __builtin_amdgcn_global_load_lds((const __attribute__((address_space(1))) void*)g,
                                     (__attribute__((address_space(3))) void*)l, 16, 0, 0);
}

// ---------------- LayerNorm (one block per row) -> bf16 out with zero-padded stride ----------------
__global__ __launch_bounds__(256) void ln_bf16(const float* __restrict__ in, int in_stride,
                                               const float* __restrict__ w, const float* __restrict__ bb,
                                               __hip_bfloat16* __restrict__ out, int out_stride, int N)
{
    int row = blockIdx.x;
    const float* ip = in + (size_t)row * in_stride;
    __hip_bfloat16* op = out + (size_t)row * out_stride;
    int tid = threadIdx.x;
    float sum = 0.f, sq = 0.f;
    for (int i = tid; i < N; i += 256) { float v = ip[i]; sum += v; sq += v * v; }
    __shared__ float s1[256], s2[256];
    s1[tid] = sum; s2[tid] = sq; __syncthreads();
    for (int s = 128; s > 0; s >>= 1) {
        if (tid < s) { s1[tid] += s1[tid + s]; s2[tid] += s2[tid + s]; }
        __syncthreads();
    }
    float mean = s1[0] / N;
    float var  = s2[0] / N - mean * mean;
    float rstd = rsqrtf(var + 1e-5f);
    for (int i = tid; i < N; i += 256) {
        float v = ip[i];
        op[i] = __float2bfloat16((v - mean) * rstd * w[i] + bb[i]);
    }
    for (int i = N + tid; i < out_stride; i += 256) op[i] = __float2bfloat16(0.f);
}

// ---------------- weight transpose + convert: W f32 [K,N] -> Wt bf16 [Npad,Kpad] (zero pad) --------
__global__ __launch_bounds__(256) void transpose_cvt(const float* __restrict__ W, __hip_bfloat16* __restrict__ Wt,
                                                     int K, int N, int Kp)
{
    __shared__ float t[32][33];
    int k0 = blockIdx.x * 32, n0 = blockIdx.y * 32;
    int tx = threadIdx.x & 31, ty = threadIdx.x >> 5;   // 8 rows/iter
    for (int r = ty; r < 32; r += 8) {
        int k = k0 + r, n = n0 + tx;
        t[r][tx] = (k < K && n < N) ? W[(size_t)k * N + n] : 0.f;
    }
    __syncthreads();
    for (int r = ty; r < 32; r += 8) {
        int n = n0 + r, k = k0 + tx;
        Wt[(size_t)n * Kp + k] = __float2bfloat16(t[tx][r]);
    }
}

// plain f32 -> bf16 convert (W_o is already [N,K])
__global__ __launch_bounds__(256) void cvt_bf16(const float* __restrict__ in, __hip_bfloat16* __restrict__ out, int n)
{
    int i = blockIdx.x * 256 + threadIdx.x;
    if (i < n) out[i] = __float2bfloat16(in[i]);
}

// ---------------- bf16 MFMA GEMM (m97 structure): C[M,N] = A[M,Kp] @ Bt[N,Kp]^T ----------------
// A: [M,Kp] bf16 row-major (Kp mult of 64, zero-padded). Bt: [Npad,Kp] bf16 (B^T layout).
// EPI: 0 plain store, 1 +resid, 2 gelu(acc+bias) , 3 C += acc + bias
template<int EPI, typename CT>
__global__ __launch_bounds__(256) void gemm_bf16(const __hip_bfloat16* __restrict__ A,
                                                 const __hip_bfloat16* __restrict__ Bt,
                                                 CT* __restrict__ C, int M, int N, int Kp, int ldc,
                                                 const float* __restrict__ bias,
                                                 const float* __restrict__ resid)
{
    __shared__ __hip_bfloat16 As[128 * 64];
    __shared__ __hip_bfloat16 Bs[128 * 64];
    int tid = threadIdx.x;
    int bm = blockIdx.y * 128;
    int bn = blockIdx.x * 128;
    int wid = tid >> 6, lane = tid & 63;
    int wm = (wid >> 1) * 64, wn = (wid & 1) * 64;
    int lrow = lane & 15;
    int kq = (lane >> 4) * 8;

    floatx4 acc[4][4];
    #pragma unroll
    for (int i = 0; i < 4; ++i)
        #pragma unroll
        for (int j = 0; j < 4; ++j)
            acc[i][j] = (floatx4){0.f, 0.f, 0.f, 0.f};

    for (int k0 = 0; k0 < Kp; k0 += 64) {
        // stage A tile (128 rows x 64 k) : 1024 chunks of 16B
        #pragma unroll
        for (int it = 0; it < 4; ++it) {
            int chunk = it * 256 + tid;
            int row = chunk >> 3, col = (chunk & 7) * 8;
            gload_lds16(A + (size_t)(bm + row) * Kp + k0 + col, &As[chunk * 8]);
        }
        #pragma unroll
        for (int it = 0; it < 4; ++it) {
            int chunk = it * 256 + tid;
            int row = chunk >> 3, col = (chunk & 7) * 8;
            gload_lds16(Bt + (size_t)(bn + row) * Kp + k0 + col, &Bs[chunk * 8]);
        }
        __syncthreads();
        #pragma unroll
        for (int kk = 0; kk < 64; kk += 32) {
            short8 a[4], b[4];
            #pragma unroll
            for (int i = 0; i < 4; ++i)
                a[i] = *(const short8*)&As[(wm + i * 16 + lrow) * 64 + kk + kq];
            #pragma unroll
            for (int j = 0; j < 4; ++j)
                b[j] = *(const short8*)&Bs[(wn + j * 16 + lrow) * 64 + kk + kq];
            #pragma unroll
            for (int i = 0; i < 4; ++i)
                #pragma unroll
                for (int j = 0; j < 4; ++j)
                    acc[i][j] = __builtin_amdgcn_mfma_f32_16x16x32_bf16(a[i], b[j], acc[i][j], 0, 0, 0);
        }
        __syncthreads();
    }

    // epilogue: C/D map col=lane&15, row=(lane>>4)*4+reg
    int cq4 = (lane >> 4) * 4;
    #pragma unroll
    for (int i = 0; i < 4; ++i) {
        #pragma unroll
        for (int j = 0; j < 4; ++j) {
            int col = bn + wn + j * 16 + lrow;
            if (col >= N) continue;
            #pragma unroll
            for (int r = 0; r < 4; ++r) {
                int rowg = bm + wm + i * 16 + cq4 + r;
                float v = acc[i][j][r];
                size_t idx = (size_t)rowg * ldc + col;
                if (EPI == 1) v += resid[idx];
                if (EPI == 2) { v += bias[col]; v = 0.5f * v * (1.f + erff(v * 0.70710678118654752f)); }
                if (EPI == 3) { v += bias[col]; v += ((const float*)C)[idx]; }
                C[idx] = (CT)v;
            }
        }
    }
}

// ---------------- RoPE ----------------
__global__ __launch_bounds__(256) void rope_q_kernel(float* __restrict__ Q)
{
    int idx = blockIdx.x * 256 + threadIdx.x;        // T*H*32
    int i = idx & 31;
    int h = (idx >> 5) & (H_ - 1);
    int t = idx >> 9;
    float f = expf(-(float)i * (9.210340371976184f / 64.0f)); // 10000^(-i/64)
    float ang = (float)(t & (S_ - 1)) * f;
    float sv, cv; sincosf(ang, &sv, &cv);
    float* p = Q + (size_t)t * D_ + h * DH_ + ND_;
    float u = p[i], v = p[i + 32];
    p[i]      = u * cv - v * sv;
    p[i + 32] = v * cv + u * sv;
}

__global__ __launch_bounds__(256) void rope_kr_kernel(const float* __restrict__ ckv, float* __restrict__ kr)
{
    int idx = blockIdx.x * 256 + threadIdx.x;        // T*32
    int i = idx & 31;
    int t = idx >> 5;
    float f = expf(-(float)i * (9.210340371976184f / 64.0f));
    float ang = (float)(t & (S_ - 1)) * f;
    float sv, cv; sincosf(ang, &sv, &cv);
    const float* src = ckv + (size_t)t * CKW_ + KVP_;
    float u = src[i], v = src[i + 32];
    kr[(size_t)t * RD_ + i]      = u * cv - v * sv;
    kr[(size_t)t * RD_ + i + 32] = v * cv + u * sv;
}

// ---------------- Attention: one wave per (b,h,q) row, online softmax; bf16 out ----------------
__global__ __launch_bounds__(256) void attn_kernel(const float* __restrict__ Q,
                                                   const float* __restrict__ KV,
                                                   const float* __restrict__ KR,
                                                   __hip_bfloat16* __restrict__ O)
{
    int wid  = (blockIdx.x * 256 + threadIdx.x) >> 6;
    int lane = threadIdx.x & 63;
    int q = wid & (S_ - 1);
    int h = (wid >> 11) & (H_ - 1);
    int b = wid >> 15;

    const float* qrow = Q + (size_t)(b * S_ + q) * D_ + h * DH_;
    float2 qv = *(const float2*)(qrow + 2 * lane);
    const float scale = 0.08838834764831845f;   // 1/sqrt(128)
    qv.x *= scale; qv.y *= scale;

    const float* kvbase = KV + (size_t)b * S_ * KVW_ + h * 192;
    const float* krbase = KR + (size_t)b * S_ * RD_;

    float m = -INFINITY, l = 0.f, a0 = 0.f, a1 = 0.f;
    for (int k = 0; k <= q; ++k) {
        const float* kvrow = kvbase + (size_t)k * KVW_;
        float2 kv2;
        if (lane < 32) kv2 = *(const float2*)(kvrow + 2 * lane);
        else           kv2 = *(const float2*)(krbase + (size_t)k * RD_ + 2 * (lane - 32));
        float part = qv.x * kv2.x + qv.y * kv2.y;
        #pragma unroll
        for (int off = 32; off > 0; off >>= 1) part += __shfl_xor(part, off);
        float mnew = fmaxf(m, part);
        float corr = __expf(m - mnew);
        float p    = __expf(part - mnew);
        float2 vv = *(const float2*)(kvrow + ND_ + 2 * lane);
        l  = l  * corr + p;
        a0 = a0 * corr + p * vv.x;
        a1 = a1 * corr + p * vv.y;
        m = mnew;
    }
    float inv = 1.0f / l;
    __hip_bfloat16* orow = O + (size_t)(b * S_ + q) * D_ + h * DH_;
    orow[2 * lane]     = __float2bfloat16(a0 * inv);
    orow[2 * lane + 1] = __float2bfloat16(a1 * inv);
}

// ---------------- Launcher ----------------
extern "C" void kernel_launch(void* const* d_in, const int* in_sizes, int n_in,
                              void* d_out, int out_size, void* d_ws, size_t ws_size,
                              hipStream_t stream)
{
    const float* x     = (const float*)d_in[0];
    const float* anw   = (const float*)d_in[1];
    const float* anb   = (const float*)d_in[2];
    const float* W_dq  = (const float*)d_in[3];
    const float* qlw   = (const float*)d_in[4];
    const float* qlb   = (const float*)d_in[5];
    const float* W_uq  = (const float*)d_in[6];
    const float* W_dkv = (const float*)d_in[7];
    const float* kvlw  = (const float*)d_in[8];
    const float* kvlb  = (const float*)d_in[9];
    const float* W_ukv = (const float*)d_in[10];
    const float* W_o   = (const float*)d_in[11];
    const float* fnw   = (const float*)d_in[12];
    const float* fnb   = (const float*)d_in[13];
    const float* W1    = (const float*)d_in[14];
    const float* b1    = (const float*)d_in[15];
    const float* W2    = (const float*)d_in[16];
    const float* b2    = (const float*)d_in[17];

    float* out0 = (float*)d_out;                     // [T, D]
    float* ckv  = out0 + (size_t)T_ * D_;            // [T, 1429]

    // ---- workspace layout ----
    float* ws  = (float*)d_ws;
    float* cq  = ws;                                  // [T,1024] f32
    float* Q   = ws + (size_t)T_ * QP_;               // [T,2048] f32
    float* kvu = ws + (size_t)T_ * (QP_ + D_);        // [T,3072] f32
    float* kr  = ws + (size_t)T_ * (QP_ + D_ + KVW_); // [T,64]  f32
    __hip_bfloat16* h_bf   = (__hip_bfloat16*)(kr + (size_t)T_ * RD_);   // [T,2048]
    __hip_bfloat16* cq_bf  = h_bf  + (size_t)T_ * D_;                    // [T,1024]
    __hip_bfloat16* kvl_bf = cq_bf + (size_t)T_ * QP_;                   // [T,1408]
    __hip_bfloat16* o_bf   = kvl_bf + (size_t)T_ * KVP_PAD;              // [T,2048]
    __hip_bfloat16* ff1_bf = (__hip_bfloat16*)ws;    // overlays cq/Q/kvu (dead by FFN): [T,8192]
    __hip_bfloat16* wdq_t  = o_bf   + (size_t)T_ * D_;        // [1024,2048]
    __hip_bfloat16* wuq_t  = wdq_t  + (size_t)QP_ * D_;       // [2048,1024]
    __hip_bfloat16* wdkv_t = wuq_t  + (size_t)D_ * QP_;       // [1536,2048]
    __hip_bfloat16* wukv_t = wdkv_t + (size_t)CKW_PAD * D_;   // [3072,1408]
    __hip_bfloat16* wo_b   = wukv_t + (size_t)KVW_ * KVP_PAD; // [2048,2048]
    __hip_bfloat16* w1_t   = wo_b   + (size_t)D_ * D_;        // [8192,2048]
    __hip_bfloat16* w2_t   = w1_t   + (size_t)FF_ * D_;       // [2048,8192]

    dim3 blk(256);

    // ---- weight prep (every launch; inputs re-poisoned) ----
    { dim3 g(D_ / 32, QP_ / 32);       transpose_cvt<<<g, blk, 0, stream>>>(W_dq,  wdq_t,  D_, QP_, D_); }
    { dim3 g(QP_ / 32, D_ / 32);       transpose_cvt<<<g, blk, 0, stream>>>(W_uq,  wuq_t,  QP_, D_, QP_); }
    { dim3 g(D_ / 32, CKW_PAD / 32);   transpose_cvt<<<g, blk, 0, stream>>>(W_dkv, wdkv_t, D_, CKW_, D_); }
    { dim3 g(KVP_PAD / 32, KVW_ / 32); transpose_cvt<<<g, blk, 0, stream>>>(W_ukv, wukv_t, KVP_, KVW_, KVP_PAD); }
    { int n = D_ * D_;                 cvt_bf16<<<(n + 255) / 256, blk, 0, stream>>>(W_o, wo_b, n); }
    { dim3 g(D_ / 32, FF_ / 32);       transpose_cvt<<<g, blk, 0, stream>>>(W1, w1_t, D_, FF_, D_); }
    { dim3 g(FF_ / 32, D_ / 32);       transpose_cvt<<<g, blk, 0, stream>>>(W2, w2_t, FF_, D_, FF_); }

    // 1. h = LN(x) -> bf16
    ln_bf16<<<T_, blk, 0, stream>>>(x, D_, anw, anb, h_bf, D_, D_);
    // 2. cq = h @ W_dq (f32 out), then LN -> bf16
    { dim3 g(QP_ / 128, T_ / 128);
      gemm_bf16<0, float><<<g, blk, 0, stream>>>(h_bf, wdq_t, cq, T_, QP_, D_, QP_, nullptr, nullptr); }
    ln_bf16<<<T_, blk, 0, stream>>>(cq, QP_, qlw, qlb, cq_bf, QP_, QP_);
    // 3. Q = cq_ln @ W_uq (f32), rope in place
    { dim3 g(D_ / 128, T_ / 128);
      gemm_bf16<0, float><<<g, blk, 0, stream>>>(cq_bf, wuq_t, Q, T_, D_, QP_, D_, nullptr, nullptr); }
    rope_q_kernel<<<(T_ * H_ * 32) / 256, blk, 0, stream>>>(Q);
    // 4. ckv = h @ W_dkv (f32 -> output 1)
    { dim3 g(CKW_PAD / 128, T_ / 128);
      gemm_bf16<0, float><<<g, blk, 0, stream>>>(h_bf, wdkv_t, ckv, T_, CKW_, D_, CKW_, nullptr, nullptr); }
    // 5. kvl = LN(ckv[:, :KVP]) -> bf16 padded to 1408
    ln_bf16<<<T_, blk, 0, stream>>>(ckv, CKW_, kvlw, kvlb, kvl_bf, KVP_PAD, KVP_);
    // 6. kvu = kvl @ W_ukv (f32)
    { dim3 g(KVW_ / 128, T_ / 128);
      gemm_bf16<0, float><<<g, blk, 0, stream>>>(kvl_bf, wukv_t, kvu, T_, KVW_, KVP_PAD, KVW_, nullptr, nullptr); }
    // 7. roped shared k_rope
    rope_kr_kernel<<<(T_ * 32) / 256, blk, 0, stream>>>(ckv, kr);
    // 8. attention -> o (bf16)
    attn_kernel<<<(B_ * H_ * S_) / 4, blk, 0, stream>>>(Q, kvu, kr, o_bf);
    // 9. out0 = o @ W_o^T + x
    { dim3 g(D_ / 128, T_ / 128);
      gemm_bf16<1, float><<<g, blk, 0, stream>>>(o_bf, wo_b, out0, T_, D_, D_, D_, nullptr, x); }
    // 10. h2 = LN(out0) -> bf16 (reuse h_bf)
    ln_bf16<<<T_, blk, 0, stream>>>(out0, D_, fnw, fnb, h_bf, D_, D_);
    // 11. ff1 = gelu(h2 @ W1 + b1) -> bf16
    { dim3 g(FF_ / 128, T_ / 128);
      gemm_bf16<2, __hip_bfloat16><<<g, blk, 0, stream>>>(h_bf, w1_t, ff1_bf, T_, FF_, D_, FF_, b1, nullptr); }
    // 12. out0 += ff1 @ W2 + b2
    { dim3 g(D_ / 128, T_ / 128);
      gemm_bf16<3, float><<<g, blk, 0, stream>>>(ff1_bf, w2_t, out0, T_, D_, FF_, D_, b2, nullptr); }
}

// Round 3
// 1309.566 us; speedup vs baseline: 9.9252x; 4.6171x over previous
//
#include <hip/hip_runtime.h>
#include <hip/hip_bf16.h>
#include <math.h>

#define B_ 2
#define S_ 2048
#define D_ 2048
#define H_ 16
#define DH_ 128
#define QP_ 1024
#define KVP_ 1365
#define RD_ 64
#define ND_ 64
#define FF_ 8192
#define T_ (B_*S_)          // 4096 tokens
#define CKW_ (KVP_+RD_)     // 1429
#define KVW_ 3072           // D + H*ND
#define KVP_PAD 1408        // 1365 -> mult of 64
#define CKW_PAD 1536        // 1429 -> mult of 128

typedef __attribute__((ext_vector_type(8))) short short8;
typedef __attribute__((ext_vector_type(4))) short sh4;
typedef __attribute__((ext_vector_type(4))) float floatx4;

__device__ __forceinline__ void gload_lds16(const __hip_bfloat16* g, __hip_bfloat16* l) {
    __builtin_amdgcn_global_load_lds((const __attribute__((address_space(1))) void*)g,
                                     (__attribute__((address_space(3))) void*)l, 16, 0, 0);
}
__device__ __forceinline__ short f2bs(float f) {
    __hip_bfloat16 h = __float2bfloat16(f);
    return *reinterpret_cast<short*>(&h);
}
// XOR-swizzled element offset into a [rows][64] bf16 LDS tile; g = 16B-group (0..7)
__device__ __forceinline__ int sw(int row, int g) { return row * 64 + ((g ^ (row & 7)) << 3); }

// ---------------- LayerNorm -> bf16 out with zero-padded stride ----------------
__global__ __launch_bounds__(256) void ln_bf16(const float* __restrict__ in, int in_stride,
                                               const float* __restrict__ w, const float* __restrict__ bb,
                                               __hip_bfloat16* __restrict__ out, int out_stride, int N)
{
    int row = blockIdx.x;
    const float* ip = in + (size_t)row * in_stride;
    __hip_bfloat16* op = out + (size_t)row * out_stride;
    int tid = threadIdx.x;
    float sum = 0.f, sq = 0.f;
    for (int i = tid; i < N; i += 256) { float v = ip[i]; sum += v; sq += v * v; }
    __shared__ float s1[256], s2[256];
    s1[tid] = sum; s2[tid] = sq; __syncthreads();
    for (int s = 128; s > 0; s >>= 1) {
        if (tid < s) { s1[tid] += s1[tid + s]; s2[tid] += s2[tid + s]; }
        __syncthreads();
    }
    float mean = s1[0] / N;
    float var  = s2[0] / N - mean * mean;
    float rstd = rsqrtf(var + 1e-5f);
    for (int i = tid; i < N; i += 256) {
        float v = ip[i];
        op[i] = __float2bfloat16((v - mean) * rstd * w[i] + bb[i]);
    }
    for (int i = N + tid; i < out_stride; i += 256) op[i] = __float2bfloat16(0.f);
}

// ---------------- weight transpose + convert: W f32 [K,N] -> Wt bf16 [Npad,Kp] ----------------
__global__ __launch_bounds__(256) void transpose_cvt(const float* __restrict__ W, __hip_bfloat16* __restrict__ Wt,
                                                     int K, int N, int Kp)
{
    __shared__ float t[32][33];
    int k0 = blockIdx.x * 32, n0 = blockIdx.y * 32;
    int tx = threadIdx.x & 31, ty = threadIdx.x >> 5;
    for (int r = ty; r < 32; r += 8) {
        int k = k0 + r, n = n0 + tx;
        t[r][tx] = (k < K && n < N) ? W[(size_t)k * N + n] : 0.f;
    }
    __syncthreads();
    for (int r = ty; r < 32; r += 8) {
        int n = n0 + r, k = k0 + tx;
        Wt[(size_t)n * Kp + k] = __float2bfloat16(t[tx][r]);
    }
}

__global__ __launch_bounds__(256) void cvt_bf16(const float* __restrict__ in, __hip_bfloat16* __restrict__ out, int n)
{
    int i = blockIdx.x * 256 + threadIdx.x;
    if (i < n) out[i] = __float2bfloat16(in[i]);
}

// ---------------- bf16 MFMA GEMM (m97 structure) ----------------
template<int EPI, typename CT>
__global__ __launch_bounds__(256) void gemm_bf16(const __hip_bfloat16* __restrict__ A,
                                                 const __hip_bfloat16* __restrict__ Bt,
                                                 CT* __restrict__ C, int M, int N, int Kp, int ldc,
                                                 const float* __restrict__ bias,
                                                 const float* __restrict__ resid)
{
    __shared__ __hip_bfloat16 As[128 * 64];
    __shared__ __hip_bfloat16 Bs[128 * 64];
    int tid = threadIdx.x;
    int bm = blockIdx.y * 128;
    int bn = blockIdx.x * 128;
    int wid = tid >> 6, lane = tid & 63;
    int wm = (wid >> 1) * 64, wn = (wid & 1) * 64;
    int lrow = lane & 15;
    int kq = (lane >> 4) * 8;

    floatx4 acc[4][4];
    #pragma unroll
    for (int i = 0; i < 4; ++i)
        #pragma unroll
        for (int j = 0; j < 4; ++j)
            acc[i][j] = (floatx4){0.f, 0.f, 0.f, 0.f};

    for (int k0 = 0; k0 < Kp; k0 += 64) {
        #pragma unroll
        for (int it = 0; it < 4; ++it) {
            int chunk = it * 256 + tid;
            int row = chunk >> 3, col = (chunk & 7) * 8;
            gload_lds16(A + (size_t)(bm + row) * Kp + k0 + col, &As[chunk * 8]);
        }
        #pragma unroll
        for (int it = 0; it < 4; ++it) {
            int chunk = it * 256 + tid;
            int row = chunk >> 3, col = (chunk & 7) * 8;
            gload_lds16(Bt + (size_t)(bn + row) * Kp + k0 + col, &Bs[chunk * 8]);
        }
        __syncthreads();
        #pragma unroll
        for (int kk = 0; kk < 64; kk += 32) {
            short8 a[4], b[4];
            #pragma unroll
            for (int i = 0; i < 4; ++i)
                a[i] = *(const short8*)&As[(wm + i * 16 + lrow) * 64 + kk + kq];
            #pragma unroll
            for (int j = 0; j < 4; ++j)
                b[j] = *(const short8*)&Bs[(wn + j * 16 + lrow) * 64 + kk + kq];
            #pragma unroll
            for (int i = 0; i < 4; ++i)
                #pragma unroll
                for (int j = 0; j < 4; ++j)
                    acc[i][j] = __builtin_amdgcn_mfma_f32_16x16x32_bf16(a[i], b[j], acc[i][j], 0, 0, 0);
        }
        __syncthreads();
    }

    int cq4 = (lane >> 4) * 4;
    #pragma unroll
    for (int i = 0; i < 4; ++i) {
        #pragma unroll
        for (int j = 0; j < 4; ++j) {
            int col = bn + wn + j * 16 + lrow;
            if (col >= N) continue;
            #pragma unroll
            for (int r = 0; r < 4; ++r) {
                int rowg = bm + wm + i * 16 + cq4 + r;
                float v = acc[i][j][r];
                size_t idx = (size_t)rowg * ldc + col;
                if (EPI == 1) v += resid[idx];
                if (EPI == 2) { v += bias[col]; v = 0.5f * v * (1.f + erff(v * 0.70710678118654752f)); }
                if (EPI == 3) { v += bias[col]; v += ((const float*)C)[idx]; }
                C[idx] = (CT)v;
            }
        }
    }
}

// ---------------- RoPE ----------------
__global__ __launch_bounds__(256) void rope_q_kernel(float* __restrict__ Q)
{
    int idx = blockIdx.x * 256 + threadIdx.x;        // T*H*32
    int i = idx & 31;
    int h = (idx >> 5) & (H_ - 1);
    int t = idx >> 9;
    float f = expf(-(float)i * (9.210340371976184f / 64.0f));
    float ang = (float)(t & (S_ - 1)) * f;
    float sv, cv; sincosf(ang, &sv, &cv);
    float* p = Q + (size_t)t * D_ + h * DH_ + ND_;
    float u = p[i], v = p[i + 32];
    p[i]      = u * cv - v * sv;
    p[i + 32] = v * cv + u * sv;
}

__global__ __launch_bounds__(256) void rope_kr_bf(const float* __restrict__ ckv, __hip_bfloat16* __restrict__ kr)
{
    int idx = blockIdx.x * 256 + threadIdx.x;        // T*32
    int i = idx & 31;
    int t = idx >> 5;
    float f = expf(-(float)i * (9.210340371976184f / 64.0f));
    float ang = (float)(t & (S_ - 1)) * f;
    float sv, cv; sincosf(ang, &sv, &cv);
    const float* src = ckv + (size_t)t * CKW_ + KVP_;
    float u = src[i], v = src[i + 32];
    kr[(size_t)t * RD_ + i]      = __float2bfloat16(u * cv - v * sv);
    kr[(size_t)t * RD_ + i + 32] = __float2bfloat16(v * cv + u * sv);
}

// ---------------- V transpose: kvu[t][h*192+64+v] -> Vt[b*H+h][v][t] (bf16) ----------------
__global__ __launch_bounds__(256) void vt_pack(const __hip_bfloat16* __restrict__ kvu,
                                               __hip_bfloat16* __restrict__ Vt)
{
    int bh = blockIdx.y; int b = bh >> 4, h = bh & 15;
    int v = threadIdx.x & 127;
    int tg = blockIdx.x * 2 + (threadIdx.x >> 7);    // t-group of 8
    int t0 = tg * 8;
    short8 o;
    #pragma unroll
    for (int j = 0; j < 8; ++j) {
        __hip_bfloat16 e = kvu[(size_t)(b * S_ + t0 + j) * KVW_ + h * 192 + 64 + v];
        o[j] = *reinterpret_cast<short*>(&e);
    }
    *(short8*)&Vt[((size_t)bh * 128 + v) * S_ + t0] = o;
}

// ---------------- Flash MFMA attention ----------------
// block = 4 waves, 128 q rows per block; wave w -> q rows [wq, wq+32)
// S^T = K Qn^T + Kr Qr^T  (C layout: col=q=lane&15, row=k=quad*4+r)
// P -> LDS (per-wave, swizzled) ; O^T = V^T P^T
__global__ __launch_bounds__(256) void attn_mfma(const float* __restrict__ Q,
                                                 const __hip_bfloat16* __restrict__ KVU,
                                                 const __hip_bfloat16* __restrict__ KR,
                                                 const __hip_bfloat16* __restrict__ VT,
                                                 __hip_bfloat16* __restrict__ O)
{
    __shared__ __hip_bfloat16 Kls[64 * 64];
    __shared__ __hip_bfloat16 Krls[64 * 64];
    __shared__ __hip_bfloat16 Vls[128 * 64];
    __shared__ __hip_bfloat16 Pls[4 * 32 * 64];

    int tid = threadIdx.x, wid = tid >> 6, lane = tid & 63;
    int lrow = lane & 15, quad = lane >> 4;
    int kq8 = quad * 8;
    int qtile = 15 - blockIdx.x;                     // biggest work first
    int bh = blockIdx.y, b = bh >> 4, h = bh & 15;
    int q0 = qtile * 128, wq = wid * 32;

    const float scale = 0.08838834764831845f;        // 1/sqrt(128)

    // Q fragments (resident): bq = Qn, bqr = roped Qr
    short8 bq[2][2], bqr[2][2];
    #pragma unroll
    for (int n = 0; n < 2; ++n) {
        const float* qrow = Q + (size_t)(b * S_ + q0 + wq + n * 16 + lrow) * D_ + h * DH_;
        #pragma unroll
        for (int s = 0; s < 2; ++s) {
            int base = s * 32 + kq8;
            #pragma unroll
            for (int j = 0; j < 8; ++j) {
                bq[n][s][j]  = f2bs(qrow[base + j] * scale);
                bqr[n][s][j] = f2bs(qrow[64 + base + j] * scale);
            }
        }
    }

    float mstate[2] = {-INFINITY, -INFINITY};
    float lstate[2] = {0.f, 0.f};
    floatx4 acco[8][2];
    #pragma unroll
    for (int vt = 0; vt < 8; ++vt)
        #pragma unroll
        for (int n = 0; n < 2; ++n)
            acco[vt][n] = (floatx4){0.f, 0.f, 0.f, 0.f};

    int nk = qtile * 2 + 2;
    int qmax_w = q0 + wq + 31;

    for (int kt = 0; kt < nk; ++kt) {
        int k0 = kt * 64;
        // stage K (8KB), Kr (8KB): 512 chunks each
        #pragma unroll
        for (int it = 0; it < 2; ++it) {
            int c = it * 256 + tid;
            int row = c >> 3, g = c & 7;
            int col = ((g ^ (row & 7)) << 3);
            gload_lds16(KVU + (size_t)(b * S_ + k0 + row) * KVW_ + h * 192 + col, &Kls[c * 8]);
            gload_lds16(KR + (size_t)(b * S_ + k0 + row) * RD_ + col, &Krls[c * 8]);
        }
        // stage V^T (16KB): 1024 chunks
        #pragma unroll
        for (int it = 0; it < 4; ++it) {
            int c = it * 256 + tid;
            int row = c >> 3, g = c & 7;
            int col = ((g ^ (row & 7)) << 3);
            gload_lds16(VT + ((size_t)bh * 128 + row) * S_ + k0 + col, &Vls[c * 8]);
        }
        __syncthreads();

        if (k0 <= qmax_w) {
            // ---- S^T = K Qn^T + Kr Qr^T ----
            floatx4 sacc[4][2];
            #pragma unroll
            for (int m = 0; m < 4; ++m)
                #pragma unroll
                for (int n = 0; n < 2; ++n)
                    sacc[m][n] = (floatx4){0.f, 0.f, 0.f, 0.f};
            #pragma unroll
            for (int m = 0; m < 4; ++m) {
                short8 ak[2], akr[2];
                #pragma unroll
                for (int s = 0; s < 2; ++s) {
                    ak[s]  = *(const short8*)&Kls[sw(m * 16 + lrow, s * 4 + quad)];
                    akr[s] = *(const short8*)&Krls[sw(m * 16 + lrow, s * 4 + quad)];
                }
                #pragma unroll
                for (int n = 0; n < 2; ++n)
                    #pragma unroll
                    for (int s = 0; s < 2; ++s) {
                        sacc[m][n] = __builtin_amdgcn_mfma_f32_16x16x32_bf16(ak[s],  bq[n][s],  sacc[m][n], 0, 0, 0);
                        sacc[m][n] = __builtin_amdgcn_mfma_f32_16x16x32_bf16(akr[s], bqr[n][s], sacc[m][n], 0, 0, 0);
                    }
            }
            // ---- online softmax per q column ----
            #pragma unroll
            for (int n = 0; n < 2; ++n) {
                int qg = q0 + wq + n * 16 + lrow;
                float tmax = -INFINITY;
                #pragma unroll
                for (int m = 0; m < 4; ++m)
                    #pragma unroll
                    for (int r = 0; r < 4; ++r) {
                        int kg = k0 + m * 16 + quad * 4 + r;
                        if (kg > qg) sacc[m][n][r] = -1e30f;
                        tmax = fmaxf(tmax, sacc[m][n][r]);
                    }
                tmax = fmaxf(tmax, __shfl_xor(tmax, 16));
                tmax = fmaxf(tmax, __shfl_xor(tmax, 32));
                float mnew = fmaxf(mstate[n], tmax);
                float alpha = __expf(mstate[n] - mnew);
                mstate[n] = mnew;
                float ps = 0.f;
                #pragma unroll
                for (int m = 0; m < 4; ++m) {
                    sh4 pk;
                    #pragma unroll
                    for (int r = 0; r < 4; ++r) {
                        float p = __expf(sacc[m][n][r] - mnew);
                        ps += p;
                        pk[r] = f2bs(p);
                    }
                    int qloc = n * 16 + lrow;
                    int off = wid * 2048 + qloc * 64 + (((m * 2 + (quad >> 1)) ^ (lrow & 7)) << 3) + ((quad & 1) << 2);
                    *(sh4*)&Pls[off] = pk;
                }
                ps += __shfl_xor(ps, 16);
                ps += __shfl_xor(ps, 32);
                lstate[n] = lstate[n] * alpha + ps;
                #pragma unroll
                for (int vt = 0; vt < 8; ++vt)
                    #pragma unroll
                    for (int r = 0; r < 4; ++r)
                        acco[vt][n][r] *= alpha;
            }
            // ---- O^T += V^T P^T ----
            short8 bp[2][2];
            #pragma unroll
            for (int n = 0; n < 2; ++n)
                #pragma unroll
                for (int s = 0; s < 2; ++s)
                    bp[n][s] = *(const short8*)&Pls[wid * 2048 + sw(n * 16 + lrow, s * 4 + quad)];
            #pragma unroll
            for (int vt = 0; vt < 8; ++vt) {
                short8 av[2];
                #pragma unroll
                for (int s = 0; s < 2; ++s)
                    av[s] = *(const short8*)&Vls[sw(vt * 16 + lrow, s * 4 + quad)];
                #pragma unroll
                for (int n = 0; n < 2; ++n)
                    #pragma unroll
                    for (int s = 0; s < 2; ++s)
                        acco[vt][n] = __builtin_amdgcn_mfma_f32_16x16x32_bf16(av[s], bp[n][s], acco[vt][n], 0, 0, 0);
            }
        }
        __syncthreads();
    }

    // ---- epilogue: O[q][v] = acco/l, bf16 ----
    #pragma unroll
    for (int n = 0; n < 2; ++n) {
        float inv = 1.0f / lstate[n];
        int tok = b * S_ + q0 + wq + n * 16 + lrow;
        #pragma unroll
        for (int vt = 0; vt < 8; ++vt) {
            sh4 o4;
            #pragma unroll
            for (int r = 0; r < 4; ++r) o4[r] = f2bs(acco[vt][n][r] * inv);
            *(sh4*)&O[(size_t)tok * D_ + h * DH_ + vt * 16 + quad * 4] = o4;
        }
    }
}

// ---------------- Launcher ----------------
extern "C" void kernel_launch(void* const* d_in, const int* in_sizes, int n_in,
                              void* d_out, int out_size, void* d_ws, size_t ws_size,
                              hipStream_t stream)
{
    const float* x     = (const float*)d_in[0];
    const float* anw   = (const float*)d_in[1];
    const float* anb   = (const float*)d_in[2];
    const float* W_dq  = (const float*)d_in[3];
    const float* qlw   = (const float*)d_in[4];
    const float* qlb   = (const float*)d_in[5];
    const float* W_uq  = (const float*)d_in[6];
    const float* W_dkv = (const float*)d_in[7];
    const float* kvlw  = (const float*)d_in[8];
    const float* kvlb  = (const float*)d_in[9];
    const float* W_ukv = (const float*)d_in[10];
    const float* W_o   = (const float*)d_in[11];
    const float* fnw   = (const float*)d_in[12];
    const float* fnb   = (const float*)d_in[13];
    const float* W1    = (const float*)d_in[14];
    const float* b1    = (const float*)d_in[15];
    const float* W2    = (const float*)d_in[16];
    const float* b2    = (const float*)d_in[17];

    float* out0 = (float*)d_out;                     // [T, D]
    float* ckv  = out0 + (size_t)T_ * D_;            // [T, 1429]

    // ---- workspace layout (Q,cq,kvu first: overlaid by ff1 in FFN phase) ----
    float* ws = (float*)d_ws;
    float* Q  = ws;                                          // [T,2048] f32
    float* cq = Q + (size_t)T_ * D_;                         // [T,1024] f32
    __hip_bfloat16* kvu_bf = (__hip_bfloat16*)(cq + (size_t)T_ * QP_);  // [T,3072]
    __hip_bfloat16* kr_bf  = kvu_bf + (size_t)T_ * KVW_;     // [T,64]
    __hip_bfloat16* Vt     = kr_bf + (size_t)T_ * RD_;       // [B*H][128][S]
    __hip_bfloat16* h_bf   = Vt + (size_t)T_ * D_;           // [T,2048]
    __hip_bfloat16* cq_bf  = h_bf + (size_t)T_ * D_;         // [T,1024]
    __hip_bfloat16* kvl_bf = cq_bf + (size_t)T_ * QP_;       // [T,1408]
    __hip_bfloat16* o_bf   = kvl_bf + (size_t)T_ * KVP_PAD;  // [T,2048]
    __hip_bfloat16* wdq_t  = o_bf + (size_t)T_ * D_;         // [1024,2048]
    __hip_bfloat16* wuq_t  = wdq_t + (size_t)QP_ * D_;       // [2048,1024]
    __hip_bfloat16* wdkv_t = wuq_t + (size_t)D_ * QP_;       // [1536,2048]
    __hip_bfloat16* wukv_t = wdkv_t + (size_t)CKW_PAD * D_;  // [3072,1408]
    __hip_bfloat16* wo_b   = wukv_t + (size_t)KVW_ * KVP_PAD;// [2048,2048]
    __hip_bfloat16* w1_t   = wo_b + (size_t)D_ * D_;         // [8192,2048]
    __hip_bfloat16* w2_t   = w1_t + (size_t)FF_ * D_;        // [2048,8192]
    __hip_bfloat16* ff1_bf = (__hip_bfloat16*)ws;            // overlays Q+cq+kvu (dead by FFN)

    dim3 blk(256);

    // ---- weight prep ----
    { dim3 g(D_ / 32, QP_ / 32);       transpose_cvt<<<g, blk, 0, stream>>>(W_dq,  wdq_t,  D_, QP_, D_); }
    { dim3 g(QP_ / 32, D_ / 32);       transpose_cvt<<<g, blk, 0, stream>>>(W_uq,  wuq_t,  QP_, D_, QP_); }
    { dim3 g(D_ / 32, CKW_PAD / 32);   transpose_cvt<<<g, blk, 0, stream>>>(W_dkv, wdkv_t, D_, CKW_, D_); }
    { dim3 g(KVP_PAD / 32, KVW_ / 32); transpose_cvt<<<g, blk, 0, stream>>>(W_ukv, wukv_t, KVP_, KVW_, KVP_PAD); }
    { int n = D_ * D_;                 cvt_bf16<<<(n + 255) / 256, blk, 0, stream>>>(W_o, wo_b, n); }
    { dim3 g(D_ / 32, FF_ / 32);       transpose_cvt<<<g, blk, 0, stream>>>(W1, w1_t, D_, FF_, D_); }
    { dim3 g(FF_ / 32, D_ / 32);       transpose_cvt<<<g, blk, 0, stream>>>(W2, w2_t, FF_, D_, FF_); }

    // 1. h = LN(x) -> bf16
    ln_bf16<<<T_, blk, 0, stream>>>(x, D_, anw, anb, h_bf, D_, D_);
    // 2. cq = h @ W_dq (f32), LN -> bf16
    { dim3 g(QP_ / 128, T_ / 128);
      gemm_bf16<0, float><<<g, blk, 0, stream>>>(h_bf, wdq_t, cq, T_, QP_, D_, QP_, nullptr, nullptr); }
    ln_bf16<<<T_, blk, 0, stream>>>(cq, QP_, qlw, qlb, cq_bf, QP_, QP_);
    // 3. Q = cq_ln @ W_uq (f32), rope in place
    { dim3 g(D_ / 128, T_ / 128);
      gemm_bf16<0, float><<<g, blk, 0, stream>>>(cq_bf, wuq_t, Q, T_, D_, QP_, D_, nullptr, nullptr); }
    rope_q_kernel<<<(T_ * H_ * 32) / 256, blk, 0, stream>>>(Q);
    // 4. ckv = h @ W_dkv (f32 -> output 1)
    { dim3 g(CKW_PAD / 128, T_ / 128);
      gemm_bf16<0, float><<<g, blk, 0, stream>>>(h_bf, wdkv_t, ckv, T_, CKW_, D_, CKW_, nullptr, nullptr); }
    // 5. kvl = LN(ckv[:, :KVP]) -> bf16 padded
    ln_bf16<<<T_, blk, 0, stream>>>(ckv, CKW_, kvlw, kvlb, kvl_bf, KVP_PAD, KVP_);
    // 6. kvu = kvl @ W_ukv -> bf16
    { dim3 g(KVW_ / 128, T_ / 128);
      gemm_bf16<0, __hip_bfloat16><<<g, blk, 0, stream>>>(kvl_bf, wukv_t, kvu_bf, T_, KVW_, KVP_PAD, KVW_, nullptr, nullptr); }
    // 7. roped k_rope (bf16) + V^T pack
    rope_kr_bf<<<(T_ * 32) / 256, blk, 0, stream>>>(ckv, kr_bf);
    { dim3 g(S_ / 16, B_ * H_);   // 2 t-groups of 8 per block (256 thr = 2 x 128 v)
      vt_pack<<<g, blk, 0, stream>>>(kvu_bf, Vt); }
    // 8. flash attention -> o (bf16)
    { dim3 g(16, B_ * H_);
      attn_mfma<<<g, blk, 0, stream>>>(Q, kvu_bf, kr_bf, Vt, o_bf); }
    // 9. out0 = o @ W_o^T + x
    { dim3 g(D_ / 128, T_ / 128);
      gemm_bf16<1, float><<<g, blk, 0, stream>>>(o_bf, wo_b, out0, T_, D_, D_, D_, nullptr, x); }
    // 10. h2 = LN(out0) -> bf16
    ln_bf16<<<T_, blk, 0, stream>>>(out0, D_, fnw, fnb, h_bf, D_, D_);
    // 11. ff1 = gelu(h2 @ W1 + b1) -> bf16
    { dim3 g(FF_ / 128, T_ / 128);
      gemm_bf16<2, __hip_bfloat16><<<g, blk, 0, stream>>>(h_bf, w1_t, ff1_bf, T_, FF_, D_, FF_, b1, nullptr); }
    // 12. out0 += ff1 @ W2 + b2
    { dim3 g(D_ / 128, T_ / 128);
      gemm_bf16<3, float><<<g, blk, 0, stream>>>(ff1_bf, w2_t, out0, T_, D_, FF_, D_, b2, nullptr); }
}

// Round 4
// 1145.219 us; speedup vs baseline: 11.3495x; 1.1435x over previous
//
#include <hip/hip_runtime.h>
#include <hip/hip_bf16.h>
#include <math.h>

#define B_ 2
#define S_ 2048
#define D_ 2048
#define H_ 16
#define DH_ 128
#define QP_ 1024
#define KVP_ 1365
#define RD_ 64
#define ND_ 64
#define FF_ 8192
#define T_ (B_*S_)          // 4096 tokens
#define CKW_ (KVP_+RD_)     // 1429
#define KVW_ 3072           // D + H*ND
#define KVP_PAD 1408        // 1365 -> mult of 64
#define CKW_PAD 1536        // 1429 -> mult of 128

typedef __attribute__((ext_vector_type(8))) short short8;
typedef __attribute__((ext_vector_type(4))) short sh4;
typedef __attribute__((ext_vector_type(4))) float floatx4;

__device__ __forceinline__ void gload_lds16(const __hip_bfloat16* g, __hip_bfloat16* l) {
    __builtin_amdgcn_global_load_lds((const __attribute__((address_space(1))) void*)g,
                                     (__attribute__((address_space(3))) void*)l, 16, 0, 0);
}
__device__ __forceinline__ short f2bs(float f) {
    __hip_bfloat16 h = __float2bfloat16(f);
    return *reinterpret_cast<short*>(&h);
}
// XOR-swizzled element offset into a [rows][64] bf16 LDS tile; g = 16B-group (0..7)
__device__ __forceinline__ int sw(int row, int g) { return row * 64 + ((g ^ (row & 7)) << 3); }

// fast gelu: 0.5*v*(1+erf(v/sqrt2)), A&S 7.1.26 erf approx (max err 1.5e-7)
__device__ __forceinline__ float fast_gelu(float v) {
    float x = v * 0.70710678118654752f;
    float ax = fabsf(x);
    float t = __builtin_amdgcn_rcpf(1.f + 0.3275911f * ax);
    float y = t * (0.254829592f + t * (-0.284496736f + t * (1.421413741f + t * (-1.453152027f + t * 1.061405429f))));
    float e = __expf(-ax * ax);
    float erfv = 1.f - y * e;
    erfv = copysignf(erfv, x);
    return 0.5f * v * (1.f + erfv);
}

// ---------------- LayerNorm -> bf16 out with zero-padded stride ----------------
__global__ __launch_bounds__(256) void ln_bf16(const float* __restrict__ in, int in_stride,
                                               const float* __restrict__ w, const float* __restrict__ bb,
                                               __hip_bfloat16* __restrict__ out, int out_stride, int N)
{
    int row = blockIdx.x;
    const float* ip = in + (size_t)row * in_stride;
    __hip_bfloat16* op = out + (size_t)row * out_stride;
    int tid = threadIdx.x;
    float sum = 0.f, sq = 0.f;
    for (int i = tid; i < N; i += 256) { float v = ip[i]; sum += v; sq += v * v; }
    __shared__ float s1[256], s2[256];
    s1[tid] = sum; s2[tid] = sq; __syncthreads();
    for (int s = 128; s > 0; s >>= 1) {
        if (tid < s) { s1[tid] += s1[tid + s]; s2[tid] += s2[tid + s]; }
        __syncthreads();
    }
    float mean = s1[0] / N;
    float var  = s2[0] / N - mean * mean;
    float rstd = rsqrtf(var + 1e-5f);
    for (int i = tid; i < N; i += 256) {
        float v = ip[i];
        op[i] = __float2bfloat16((v - mean) * rstd * w[i] + bb[i]);
    }
    for (int i = N + tid; i < out_stride; i += 256) op[i] = __float2bfloat16(0.f);
}

// ---------------- weight transpose + convert: W f32 [K,N] -> Wt bf16 [Npad,Kp] ----------------
__global__ __launch_bounds__(256) void transpose_cvt(const float* __restrict__ W, __hip_bfloat16* __restrict__ Wt,
                                                     int K, int N, int Kp)
{
    __shared__ float t[32][33];
    int k0 = blockIdx.x * 32, n0 = blockIdx.y * 32;
    int tx = threadIdx.x & 31, ty = threadIdx.x >> 5;
    for (int r = ty; r < 32; r += 8) {
        int k = k0 + r, n = n0 + tx;
        t[r][tx] = (k < K && n < N) ? W[(size_t)k * N + n] : 0.f;
    }
    __syncthreads();
    for (int r = ty; r < 32; r += 8) {
        int n = n0 + r, k = k0 + tx;
        Wt[(size_t)n * Kp + k] = __float2bfloat16(t[tx][r]);
    }
}

__global__ __launch_bounds__(256) void cvt_bf16(const float* __restrict__ in, __hip_bfloat16* __restrict__ out, int n)
{
    int i = blockIdx.x * 256 + threadIdx.x;
    if (i < n) out[i] = __float2bfloat16(in[i]);
}

// ---------------- bf16 MFMA GEMM (m97 structure + XOR-swizzled LDS) ----------------
// A: [M,Kp] bf16 row-major. Bt: [Npad,Kp] bf16 (B^T). Tiles staged with the 16B-group
// XOR swizzle applied to the GLOBAL k-offset (DMA dest stays contiguous, m104-safe);
// fragment reads un-swizzle via sw(row, group) -> 2-way-max bank aliasing (free).
template<int EPI, typename CT>
__global__ __launch_bounds__(256) void gemm_bf16(const __hip_bfloat16* __restrict__ A,
                                                 const __hip_bfloat16* __restrict__ Bt,
                                                 CT* __restrict__ C, int M, int N, int Kp, int ldc,
                                                 const float* __restrict__ bias,
                                                 const float* __restrict__ resid)
{
    __shared__ __hip_bfloat16 As[128 * 64];
    __shared__ __hip_bfloat16 Bs[128 * 64];
    int tid = threadIdx.x;
    int bm = blockIdx.y * 128;
    int bn = blockIdx.x * 128;
    int wid = tid >> 6, lane = tid & 63;
    int wm = (wid >> 1) * 64, wn = (wid & 1) * 64;
    int lrow = lane & 15;
    int quad = lane >> 4;

    floatx4 acc[4][4];
    #pragma unroll
    for (int i = 0; i < 4; ++i)
        #pragma unroll
        for (int j = 0; j < 4; ++j)
            acc[i][j] = (floatx4){0.f, 0.f, 0.f, 0.f};

    for (int k0 = 0; k0 < Kp; k0 += 64) {
        #pragma unroll
        for (int it = 0; it < 4; ++it) {
            int chunk = it * 256 + tid;
            int row = chunk >> 3, g = chunk & 7;
            int col = (g ^ (row & 7)) << 3;
            gload_lds16(A + (size_t)(bm + row) * Kp + k0 + col, &As[chunk * 8]);
        }
        #pragma unroll
        for (int it = 0; it < 4; ++it) {
            int chunk = it * 256 + tid;
            int row = chunk >> 3, g = chunk & 7;
            int col = (g ^ (row & 7)) << 3;
            gload_lds16(Bt + (size_t)(bn + row) * Kp + k0 + col, &Bs[chunk * 8]);
        }
        __syncthreads();
        #pragma unroll
        for (int kk = 0; kk < 2; ++kk) {       // k-group s = kk*4 + quad
            short8 a[4], b[4];
            #pragma unroll
            for (int i = 0; i < 4; ++i)
                a[i] = *(const short8*)&As[sw(wm + i * 16 + lrow, kk * 4 + quad)];
            #pragma unroll
            for (int j = 0; j < 4; ++j)
                b[j] = *(const short8*)&Bs[sw(wn + j * 16 + lrow, kk * 4 + quad)];
            #pragma unroll
            for (int i = 0; i < 4; ++i)
                #pragma unroll
                for (int j = 0; j < 4; ++j)
                    acc[i][j] = __builtin_amdgcn_mfma_f32_16x16x32_bf16(a[i], b[j], acc[i][j], 0, 0, 0);
        }
        __syncthreads();
    }

    int cq4 = quad * 4;
    #pragma unroll
    for (int i = 0; i < 4; ++i) {
        #pragma unroll
        for (int j = 0; j < 4; ++j) {
            int col = bn + wn + j * 16 + lrow;
            if (col >= N) continue;
            #pragma unroll
            for (int r = 0; r < 4; ++r) {
                int rowg = bm + wm + i * 16 + cq4 + r;
                float v = acc[i][j][r];
                size_t idx = (size_t)rowg * ldc + col;
                if (EPI == 1) v += resid[idx];
                if (EPI == 2) { v += bias[col]; v = fast_gelu(v); }
                if (EPI == 3) { v += bias[col]; v += ((const float*)C)[idx]; }
                C[idx] = (CT)v;
            }
        }
    }
}

// ---------------- RoPE ----------------
__global__ __launch_bounds__(256) void rope_q_kernel(float* __restrict__ Q)
{
    int idx = blockIdx.x * 256 + threadIdx.x;        // T*H*32
    int i = idx & 31;
    int h = (idx >> 5) & (H_ - 1);
    int t = idx >> 9;
    float f = expf(-(float)i * (9.210340371976184f / 64.0f));
    float ang = (float)(t & (S_ - 1)) * f;
    float sv, cv; sincosf(ang, &sv, &cv);
    float* p = Q + (size_t)t * D_ + h * DH_ + ND_;
    float u = p[i], v = p[i + 32];
    p[i]      = u * cv - v * sv;
    p[i + 32] = v * cv + u * sv;
}

__global__ __launch_bounds__(256) void rope_kr_bf(const float* __restrict__ ckv, __hip_bfloat16* __restrict__ kr)
{
    int idx = blockIdx.x * 256 + threadIdx.x;        // T*32
    int i = idx & 31;
    int t = idx >> 5;
    float f = expf(-(float)i * (9.210340371976184f / 64.0f));
    float ang = (float)(t & (S_ - 1)) * f;
    float sv, cv; sincosf(ang, &sv, &cv);
    const float* src = ckv + (size_t)t * CKW_ + KVP_;
    float u = src[i], v = src[i + 32];
    kr[(size_t)t * RD_ + i]      = __float2bfloat16(u * cv - v * sv);
    kr[(size_t)t * RD_ + i + 32] = __float2bfloat16(v * cv + u * sv);
}

// ---------------- V transpose: kvu[t][h*192+64+v] -> Vt[b*H+h][v][t] (bf16) ----------------
__global__ __launch_bounds__(256) void vt_pack(const __hip_bfloat16* __restrict__ kvu,
                                               __hip_bfloat16* __restrict__ Vt)
{
    int bh = blockIdx.y; int b = bh >> 4, h = bh & 15;
    int v = threadIdx.x & 127;
    int tg = blockIdx.x * 2 + (threadIdx.x >> 7);
    int t0 = tg * 8;
    short8 o;
    #pragma unroll
    for (int j = 0; j < 8; ++j) {
        __hip_bfloat16 e = kvu[(size_t)(b * S_ + t0 + j) * KVW_ + h * 192 + 64 + v];
        o[j] = *reinterpret_cast<short*>(&e);
    }
    *(short8*)&Vt[((size_t)bh * 128 + v) * S_ + t0] = o;
}

// ---------------- Flash MFMA attention ----------------
__global__ __launch_bounds__(256) void attn_mfma(const float* __restrict__ Q,
                                                 const __hip_bfloat16* __restrict__ KVU,
                                                 const __hip_bfloat16* __restrict__ KR,
                                                 const __hip_bfloat16* __restrict__ VT,
                                                 __hip_bfloat16* __restrict__ O)
{
    __shared__ __hip_bfloat16 Kls[64 * 64];
    __shared__ __hip_bfloat16 Krls[64 * 64];
    __shared__ __hip_bfloat16 Vls[128 * 64];
    __shared__ __hip_bfloat16 Pls[4 * 32 * 64];

    int tid = threadIdx.x, wid = tid >> 6, lane = tid & 63;
    int lrow = lane & 15, quad = lane >> 4;
    int kq8 = quad * 8;
    int qtile = 15 - blockIdx.x;
    int bh = blockIdx.y, b = bh >> 4, h = bh & 15;
    int q0 = qtile * 128, wq = wid * 32;

    const float scale = 0.08838834764831845f;

    short8 bq[2][2], bqr[2][2];
    #pragma unroll
    for (int n = 0; n < 2; ++n) {
        const float* qrow = Q + (size_t)(b * S_ + q0 + wq + n * 16 + lrow) * D_ + h * DH_;
        #pragma unroll
        for (int s = 0; s < 2; ++s) {
            int base = s * 32 + kq8;
            #pragma unroll
            for (int j = 0; j < 8; ++j) {
                bq[n][s][j]  = f2bs(qrow[base + j] * scale);
                bqr[n][s][j] = f2bs(qrow[64 + base + j] * scale);
            }
        }
    }

    float mstate[2] = {-INFINITY, -INFINITY};
    float lstate[2] = {0.f, 0.f};
    floatx4 acco[8][2];
    #pragma unroll
    for (int vt = 0; vt < 8; ++vt)
        #pragma unroll
        for (int n = 0; n < 2; ++n)
            acco[vt][n] = (floatx4){0.f, 0.f, 0.f, 0.f};

    int nk = qtile * 2 + 2;
    int qmax_w = q0 + wq + 31;

    for (int kt = 0; kt < nk; ++kt) {
        int k0 = kt * 64;
        #pragma unroll
        for (int it = 0; it < 2; ++it) {
            int c = it * 256 + tid;
            int row = c >> 3, g = c & 7;
            int col = ((g ^ (row & 7)) << 3);
            gload_lds16(KVU + (size_t)(b * S_ + k0 + row) * KVW_ + h * 192 + col, &Kls[c * 8]);
            gload_lds16(KR + (size_t)(b * S_ + k0 + row) * RD_ + col, &Krls[c * 8]);
        }
        #pragma unroll
        for (int it = 0; it < 4; ++it) {
            int c = it * 256 + tid;
            int row = c >> 3, g = c & 7;
            int col = ((g ^ (row & 7)) << 3);
            gload_lds16(VT + ((size_t)bh * 128 + row) * S_ + k0 + col, &Vls[c * 8]);
        }
        __syncthreads();

        if (k0 <= qmax_w) {
            floatx4 sacc[4][2];
            #pragma unroll
            for (int m = 0; m < 4; ++m)
                #pragma unroll
                for (int n = 0; n < 2; ++n)
                    sacc[m][n] = (floatx4){0.f, 0.f, 0.f, 0.f};
            #pragma unroll
            for (int m = 0; m < 4; ++m) {
                short8 ak[2], akr[2];
                #pragma unroll
                for (int s = 0; s < 2; ++s) {
                    ak[s]  = *(const short8*)&Kls[sw(m * 16 + lrow, s * 4 + quad)];
                    akr[s] = *(const short8*)&Krls[sw(m * 16 + lrow, s * 4 + quad)];
                }
                #pragma unroll
                for (int n = 0; n < 2; ++n)
                    #pragma unroll
                    for (int s = 0; s < 2; ++s) {
                        sacc[m][n] = __builtin_amdgcn_mfma_f32_16x16x32_bf16(ak[s],  bq[n][s],  sacc[m][n], 0, 0, 0);
                        sacc[m][n] = __builtin_amdgcn_mfma_f32_16x16x32_bf16(akr[s], bqr[n][s], sacc[m][n], 0, 0, 0);
                    }
            }
            #pragma unroll
            for (int n = 0; n < 2; ++n) {
                int qg = q0 + wq + n * 16 + lrow;
                float tmax = -INFINITY;
                #pragma unroll
                for (int m = 0; m < 4; ++m)
                    #pragma unroll
                    for (int r = 0; r < 4; ++r) {
                        int kg = k0 + m * 16 + quad * 4 + r;
                        if (kg > qg) sacc[m][n][r] = -1e30f;
                        tmax = fmaxf(tmax, sacc[m][n][r]);
                    }
                tmax = fmaxf(tmax, __shfl_xor(tmax, 16));
                tmax = fmaxf(tmax, __shfl_xor(tmax, 32));
                float mnew = fmaxf(mstate[n], tmax);
                float alpha = __expf(mstate[n] - mnew);
                mstate[n] = mnew;
                float ps = 0.f;
                #pragma unroll
                for (int m = 0; m < 4; ++m) {
                    sh4 pk;
                    #pragma unroll
                    for (int r = 0; r < 4; ++r) {
                        float p = __expf(sacc[m][n][r] - mnew);
                        ps += p;
                        pk[r] = f2bs(p);
                    }
                    int qloc = n * 16 + lrow;
                    int off = wid * 2048 + qloc * 64 + (((m * 2 + (quad >> 1)) ^ (lrow & 7)) << 3) + ((quad & 1) << 2);
                    *(sh4*)&Pls[off] = pk;
                }
                ps += __shfl_xor(ps, 16);
                ps += __shfl_xor(ps, 32);
                lstate[n] = lstate[n] * alpha + ps;
                #pragma unroll
                for (int vt = 0; vt < 8; ++vt)
                    #pragma unroll
                    for (int r = 0; r < 4; ++r)
                        acco[vt][n][r] *= alpha;
            }
            short8 bp[2][2];
            #pragma unroll
            for (int n = 0; n < 2; ++n)
                #pragma unroll
                for (int s = 0; s < 2; ++s)
                    bp[n][s] = *(const short8*)&Pls[wid * 2048 + sw(n * 16 + lrow, s * 4 + quad)];
            #pragma unroll
            for (int vt = 0; vt < 8; ++vt) {
                short8 av[2];
                #pragma unroll
                for (int s = 0; s < 2; ++s)
                    av[s] = *(const short8*)&Vls[sw(vt * 16 + lrow, s * 4 + quad)];
                #pragma unroll
                for (int n = 0; n < 2; ++n)
                    #pragma unroll
                    for (int s = 0; s < 2; ++s)
                        acco[vt][n] = __builtin_amdgcn_mfma_f32_16x16x32_bf16(av[s], bp[n][s], acco[vt][n], 0, 0, 0);
            }
        }
        __syncthreads();
    }

    #pragma unroll
    for (int n = 0; n < 2; ++n) {
        float inv = 1.0f / lstate[n];
        int tok = b * S_ + q0 + wq + n * 16 + lrow;
        #pragma unroll
        for (int vt = 0; vt < 8; ++vt) {
            sh4 o4;
            #pragma unroll
            for (int r = 0; r < 4; ++r) o4[r] = f2bs(acco[vt][n][r] * inv);
            *(sh4*)&O[(size_t)tok * D_ + h * DH_ + vt * 16 + quad * 4] = o4;
        }
    }
}

// ---------------- Launcher ----------------
extern "C" void kernel_launch(void* const* d_in, const int* in_sizes, int n_in,
                              void* d_out, int out_size, void* d_ws, size_t ws_size,
                              hipStream_t stream)
{
    const float* x     = (const float*)d_in[0];
    const float* anw   = (const float*)d_in[1];
    const float* anb   = (const float*)d_in[2];
    const float* W_dq  = (const float*)d_in[3];
    const float* qlw   = (const float*)d_in[4];
    const float* qlb   = (const float*)d_in[5];
    const float* W_uq  = (const float*)d_in[6];
    const float* W_dkv = (const float*)d_in[7];
    const float* kvlw  = (const float*)d_in[8];
    const float* kvlb  = (const float*)d_in[9];
    const float* W_ukv = (const float*)d_in[10];
    const float* W_o   = (const float*)d_in[11];
    const float* fnw   = (const float*)d_in[12];
    const float* fnb   = (const float*)d_in[13];
    const float* W1    = (const float*)d_in[14];
    const float* b1    = (const float*)d_in[15];
    const float* W2    = (const float*)d_in[16];
    const float* b2    = (const float*)d_in[17];

    float* out0 = (float*)d_out;                     // [T, D]
    float* ckv  = out0 + (size_t)T_ * D_;            // [T, 1429]

    float* ws = (float*)d_ws;
    float* Q  = ws;                                          // [T,2048] f32
    float* cq = Q + (size_t)T_ * D_;                         // [T,1024] f32
    __hip_bfloat16* kvu_bf = (__hip_bfloat16*)(cq + (size_t)T_ * QP_);  // [T,3072]
    __hip_bfloat16* kr_bf  = kvu_bf + (size_t)T_ * KVW_;     // [T,64]
    __hip_bfloat16* Vt     = kr_bf + (size_t)T_ * RD_;       // [B*H][128][S]
    __hip_bfloat16* h_bf   = Vt + (size_t)T_ * D_;           // [T,2048]
    __hip_bfloat16* cq_bf  = h_bf + (size_t)T_ * D_;         // [T,1024]
    __hip_bfloat16* kvl_bf = cq_bf + (size_t)T_ * QP_;       // [T,1408]
    __hip_bfloat16* o_bf   = kvl_bf + (size_t)T_ * KVP_PAD;  // [T,2048]
    __hip_bfloat16* wdq_t  = o_bf + (size_t)T_ * D_;         // [1024,2048]
    __hip_bfloat16* wuq_t  = wdq_t + (size_t)QP_ * D_;       // [2048,1024]
    __hip_bfloat16* wdkv_t = wuq_t + (size_t)D_ * QP_;       // [1536,2048]
    __hip_bfloat16* wukv_t = wdkv_t + (size_t)CKW_PAD * D_;  // [3072,1408]
    __hip_bfloat16* wo_b   = wukv_t + (size_t)KVW_ * KVP_PAD;// [2048,2048]
    __hip_bfloat16* w1_t   = wo_b + (size_t)D_ * D_;         // [8192,2048]
    __hip_bfloat16* w2_t   = w1_t + (size_t)FF_ * D_;        // [2048,8192]
    __hip_bfloat16* ff1_bf = (__hip_bfloat16*)ws;            // overlays Q+cq+kvu (dead by FFN)

    dim3 blk(256);

    { dim3 g(D_ / 32, QP_ / 32);       transpose_cvt<<<g, blk, 0, stream>>>(W_dq,  wdq_t,  D_, QP_, D_); }
    { dim3 g(QP_ / 32, D_ / 32);       transpose_cvt<<<g, blk, 0, stream>>>(W_uq,  wuq_t,  QP_, D_, QP_); }
    { dim3 g(D_ / 32, CKW_PAD / 32);   transpose_cvt<<<g, blk, 0, stream>>>(W_dkv, wdkv_t, D_, CKW_, D_); }
    { dim3 g(KVP_PAD / 32, KVW_ / 32); transpose_cvt<<<g, blk, 0, stream>>>(W_ukv, wukv_t, KVP_, KVW_, KVP_PAD); }
    { int n = D_ * D_;                 cvt_bf16<<<(n + 255) / 256, blk, 0, stream>>>(W_o, wo_b, n); }
    { dim3 g(D_ / 32, FF_ / 32);       transpose_cvt<<<g, blk, 0, stream>>>(W1, w1_t, D_, FF_, D_); }
    { dim3 g(FF_ / 32, D_ / 32);       transpose_cvt<<<g, blk, 0, stream>>>(W2, w2_t, FF_, D_, FF_); }

    ln_bf16<<<T_, blk, 0, stream>>>(x, D_, anw, anb, h_bf, D_, D_);
    { dim3 g(QP_ / 128, T_ / 128);
      gemm_bf16<0, float><<<g, blk, 0, stream>>>(h_bf, wdq_t, cq, T_, QP_, D_, QP_, nullptr, nullptr); }
    ln_bf16<<<T_, blk, 0, stream>>>(cq, QP_, qlw, qlb, cq_bf, QP_, QP_);
    { dim3 g(D_ / 128, T_ / 128);
      gemm_bf16<0, float><<<g, blk, 0, stream>>>(cq_bf, wuq_t, Q, T_, D_, QP_, D_, nullptr, nullptr); }
    rope_q_kernel<<<(T_ * H_ * 32) / 256, blk, 0, stream>>>(Q);
    { dim3 g(CKW_PAD / 128, T_ / 128);
      gemm_bf16<0, float><<<g, blk, 0, stream>>>(h_bf, wdkv_t, ckv, T_, CKW_, D_, CKW_, nullptr, nullptr); }
    ln_bf16<<<T_, blk, 0, stream>>>(ckv, CKW_, kvlw, kvlb, kvl_bf, KVP_PAD, KVP_);
    { dim3 g(KVW_ / 128, T_ / 128);
      gemm_bf16<0, __hip_bfloat16><<<g, blk, 0, stream>>>(kvl_bf, wukv_t, kvu_bf, T_, KVW_, KVP_PAD, KVW_, nullptr, nullptr); }
    rope_kr_bf<<<(T_ * 32) / 256, blk, 0, stream>>>(ckv, kr_bf);
    { dim3 g(S_ / 16, B_ * H_);
      vt_pack<<<g, blk, 0, stream>>>(kvu_bf, Vt); }
    { dim3 g(16, B_ * H_);
      attn_mfma<<<g, blk, 0, stream>>>(Q, kvu_bf, kr_bf, Vt, o_bf); }
    { dim3 g(D_ / 128, T_ / 128);
      gemm_bf16<1, float><<<g, blk, 0, stream>>>(o_bf, wo_b, out0, T_, D_, D_, D_, nullptr, x); }
    ln_bf16<<<T_, blk, 0, stream>>>(out0, D_, fnw, fnb, h_bf, D_, D_);
    { dim3 g(FF_ / 128, T_ / 128);
      gemm_bf16<2, __hip_bfloat16><<<g, blk, 0, stream>>>(h_bf, w1_t, ff1_bf, T_, FF_, D_, FF_, b1, nullptr); }
    { dim3 g(D_ / 128, T_ / 128);
      gemm_bf16<3, float><<<g, blk, 0, stream>>>(ff1_bf, w2_t, out0, T_, D_, FF_, D_, b2, nullptr); }
}